// Round 2
// baseline (466.748 us; speedup 1.0000x reference)
//
#include <hip/hip_runtime.h>

// GCN encoder: out = A' relu(A' (x W1) + b1) W2 + b2, A' = D^-1/2 (A+I) D^-1/2
// Round 2: replace 51.2M f32 atomics (atomic-throughput bound, WRITE_SIZE==4B*atomics)
// with a per-call CSR build (hist + scan + scatter, 3.2M int atomics total) and
// atomic-free wave-per-node gather-reduce, reused by both layers.
// Algebra: pre-scale g = h*dinv  =>  p[d] = dinv[d] * (g[d] + sum_{s->d} g[s]).

#define NN 100000
#define NE 1600000
#define FI 128
#define FH 16
#define NB_SCAN 391              // ceil(NN/256); 391*256 = 100096

__global__ void k_zero(int* __restrict__ cnt, int n) {
    int i = blockIdx.x * blockDim.x + threadIdx.x;
    if (i < n) cnt[i] = 0;
}

__global__ void k_hist(const int* __restrict__ dst, int* __restrict__ cnt, int e) {
    int i = blockIdx.x * blockDim.x + threadIdx.x;
    if (i < e) atomicAdd(&cnt[dst[i]], 1);
}

// per-256-block exclusive scan; write partials + block total
__global__ __launch_bounds__(256) void k_scan1(const int* __restrict__ cnt,
                                               int* __restrict__ partial,
                                               int* __restrict__ blockSums) {
    __shared__ int s[256];
    int tid = threadIdx.x;
    int i = blockIdx.x * 256 + tid;
    int v = (i < NN) ? cnt[i] : 0;
    s[tid] = v;
    __syncthreads();
    #pragma unroll
    for (int off = 1; off < 256; off <<= 1) {
        int t = (tid >= off) ? s[tid - off] : 0;
        __syncthreads();
        s[tid] += t;
        __syncthreads();
    }
    partial[i] = s[tid] - v;                 // exclusive
    if (tid == 255) blockSums[blockIdx.x] = s[255];
}

// single-block scan of the 391 block sums (padded to 512)
__global__ __launch_bounds__(512) void k_scan2(int* __restrict__ blockSums) {
    __shared__ int s[512];
    int tid = threadIdx.x;
    int v = (tid < NB_SCAN) ? blockSums[tid] : 0;
    s[tid] = v;
    __syncthreads();
    #pragma unroll
    for (int off = 1; off < 512; off <<= 1) {
        int t = (tid >= off) ? s[tid - off] : 0;
        __syncthreads();
        s[tid] += t;
        __syncthreads();
    }
    if (tid < NB_SCAN) blockSums[tid] = s[tid] - v;   // exclusive
}

// finalize rowStart, init scatter cursor, compute dinv = rsqrt(deg+1)
__global__ void k_scan3(const int* __restrict__ cnt, int* __restrict__ rowStart,
                        const int* __restrict__ blockSums, int* __restrict__ cursor,
                        float* __restrict__ dinv) {
    int i = blockIdx.x * blockDim.x + threadIdx.x;
    if (i < NN) {
        int val = rowStart[i] + blockSums[i >> 8];
        rowStart[i] = val;
        cursor[i] = val;
        dinv[i] = rsqrtf((float)(cnt[i] + 1));
    }
}

__global__ void k_scatter(const int* __restrict__ src, const int* __restrict__ dst,
                          int* __restrict__ cursor, int* __restrict__ ssrc, int e) {
    int i = blockIdx.x * blockDim.x + threadIdx.x;
    if (i < e) {
        int pos = atomicAdd(&cursor[dst[i]], 1);
        ssrc[pos] = src[i];
    }
}

// g1[n,16] = (x[n,128] @ W1[128,16]) * dinv[n]; 16 nodes/block, 16 threads/node
__global__ __launch_bounds__(256) void k_gemm1(const float* __restrict__ x,
                                               const float* __restrict__ W1,
                                               const float* __restrict__ dinv,
                                               float* __restrict__ g1, int n) {
    __shared__ float w[FI * FH];        // 2048 f32
    __shared__ float xs[16 * 132];      // stride 132 kills stride-128 bank alias
    for (int i = threadIdx.x; i < FI * FH; i += 256) w[i] = W1[i];
    int nodeBase = blockIdx.x * 16;
    for (int i = threadIdx.x; i < 16 * FI; i += 256) {
        int node = i >> 7, k = i & 127;
        int g = nodeBase + node;
        xs[node * 132 + k] = (g < n) ? x[g * FI + k] : 0.0f;
    }
    __syncthreads();
    int ln = threadIdx.x >> 4;
    int j  = threadIdx.x & 15;
    float acc = 0.0f;
    #pragma unroll
    for (int k = 0; k < FI; ++k) acc += xs[ln * 132 + k] * w[k * FH + j];
    int g = nodeBase + ln;
    if (g < n) g1[g * FH + j] = acc * dinv[g];
}

// p[d,f] = dinv[d] * (g[d,f] + sum_{e in row d} g[ssrc[e], f])
// one wave per node: 4 edge-slots x 16 features; no atomics.
__global__ __launch_bounds__(256) void k_agg(const int* __restrict__ ssrc,
                                             const int* __restrict__ rowStart,
                                             const float* __restrict__ g,
                                             const float* __restrict__ dinv,
                                             float* __restrict__ p) {
    int node = blockIdx.x * 4 + (threadIdx.x >> 6);
    if (node >= NN) return;
    int lane = threadIdx.x & 63;
    int es = lane >> 4;                 // edge slot 0..3
    int f  = lane & 15;                 // feature
    int start = rowStart[node];
    int end   = (node + 1 < NN) ? rowStart[node + 1] : NE;
    float acc = (es == 0) ? g[node * FH + f] : 0.0f;   // self-loop term
    for (int e = start + es; e < end; e += 4)
        acc += g[ssrc[e] * FH + f];
    acc += __shfl_down(acc, 32, 64);
    acc += __shfl_down(acc, 16, 64);
    if (lane < 16) p[node * FH + f] = acc * dinv[node];
}

// g2[i] = relu(p1[i] + b1[f]) * dinv[n]   (overwrites g buffer)
__global__ void k_relu_scale(const float* __restrict__ p1, const float* __restrict__ b1,
                             const float* __restrict__ dinv, float* __restrict__ g2,
                             int n16) {
    int i = blockIdx.x * blockDim.x + threadIdx.x;
    if (i < n16) {
        float v = p1[i] + b1[i & 15];
        v = v > 0.0f ? v : 0.0f;
        g2[i] = v * dinv[i >> 4];
    }
}

// out[n,128] = p2[n,16] @ W2[16,128] + b2; 2 nodes/block, 128 threads/node
__global__ __launch_bounds__(256) void k_gemm2(const float* __restrict__ p2,
                                               const float* __restrict__ W2,
                                               const float* __restrict__ b2,
                                               float* __restrict__ out, int n) {
    __shared__ float w[FH * FI];
    __shared__ float ps[2 * FH];
    for (int i = threadIdx.x; i < FH * FI; i += 256) w[i] = W2[i];
    int nodeBase = blockIdx.x * 2;
    if (threadIdx.x < 32) {
        int node = threadIdx.x >> 4, k = threadIdx.x & 15;
        int g = nodeBase + node;
        ps[threadIdx.x] = (g < n) ? p2[g * FH + k] : 0.0f;
    }
    __syncthreads();
    int ln = threadIdx.x >> 7;
    int j  = threadIdx.x & 127;
    float acc = b2[j];
    #pragma unroll
    for (int k = 0; k < FH; ++k) acc += ps[ln * FH + k] * w[k * FI + j];
    int g = nodeBase + ln;
    if (g < n) out[g * FI + j] = acc;
}

extern "C" void kernel_launch(void* const* d_in, const int* in_sizes, int n_in,
                              void* d_out, int out_size, void* d_ws, size_t ws_size,
                              hipStream_t stream) {
    const float* x  = (const float*)d_in[0];
    const int*   ei = (const int*)d_in[1];
    const float* W1 = (const float*)d_in[2];
    const float* b1 = (const float*)d_in[3];
    const float* W2 = (const float*)d_in[4];
    const float* b2 = (const float*)d_in[5];
    float* out = (float*)d_out;

    const int* src = ei;
    const int* dst = ei + NE;

    // ws layout (4B units): ~20.8 MB total
    int*   cnt       = (int*)d_ws;                 // [100096]
    int*   rowStart  = cnt + 100096;               // [100096]
    int*   cursor    = rowStart + 100096;          // [100096]
    int*   blockSums = cursor + 100096;            // [512]
    float* dinv      = (float*)(blockSums + 512);  // [NN]
    int*   ssrc      = (int*)(dinv + NN);          // [NE]
    float* g         = (float*)(ssrc + NE);        // [NN*16]
    float* p         = g + NN * FH;                // [NN*16]

    const int n16 = NN * FH;

    k_zero      <<<(NN + 255) / 256, 256, 0, stream>>>(cnt, NN);
    k_hist      <<<(NE + 255) / 256, 256, 0, stream>>>(dst, cnt, NE);
    k_scan1     <<<NB_SCAN, 256, 0, stream>>>(cnt, rowStart, blockSums);
    k_scan2     <<<1, 512, 0, stream>>>(blockSums);
    k_scan3     <<<(NN + 255) / 256, 256, 0, stream>>>(cnt, rowStart, blockSums, cursor, dinv);
    k_scatter   <<<(NE + 255) / 256, 256, 0, stream>>>(src, dst, cursor, ssrc, NE);

    k_gemm1     <<<(NN + 15) / 16, 256, 0, stream>>>(x, W1, dinv, g, NN);
    k_agg       <<<(NN + 3) / 4, 256, 0, stream>>>(ssrc, rowStart, g, dinv, p);
    k_relu_scale<<<(n16 + 255) / 256, 256, 0, stream>>>(p, b1, dinv, g, n16);
    k_agg       <<<(NN + 3) / 4, 256, 0, stream>>>(ssrc, rowStart, g, dinv, p);
    k_gemm2     <<<(NN + 1) / 2, 256, 0, stream>>>(p, W2, b2, out, NN);
}